// Round 18
// baseline (1884.703 us; speedup 1.0000x reference)
//
#include <hip/hip_runtime.h>
#include <hip/hip_bf16.h>

// SAGEClassifier: h[50000,256] --conv1(LSTM-agg)--> h1[50000,128] --conv2--> h2[50000,128]
//   --segment_max(256 graphs)--> hg[256,128] --linear--> out[256,10]
//
// Round 18: r13's W-sharing retried NOW THAT IT CAN FIT. r13 (512-thr, TN=64,
// node-halves share W) failed because demand ~150 > the 128-reg cap 512-thr blocks
// impose; r14's unroll-2 cut demand to 108 < 128. This round = r14's per-thread code
// + r13's 8-wave node-half structure: waves w and w+4 read the SAME packed-W bytes
// (L1/L2-hot second read; W L2 traffic halves, 12->6GB conv1).
// Spill tripwire: WRITE_SIZE must stay ~25MB (r13 showed 275MB when spilling).
// GEMMs keep r17's 128-col tiles (neutral). LSTM math/gather pipeline unchanged.

#define NNODES  50000
#define DEG     16
#define INDIM   256
#define HIDDIM  128
#define NCLS    10
#define NGRAPH  256

typedef __hip_bfloat16 bf16;
typedef short bf16x8 __attribute__((ext_vector_type(8)));
typedef float f32x4  __attribute__((ext_vector_type(4)));

__device__ __forceinline__ float sigf(float x) {
    float e = __builtin_amdgcn_exp2f(-1.44269504f * x);
    return __builtin_amdgcn_rcpf(1.0f + e);
}
__device__ __forceinline__ float tanhf_(float x) {
    x = fminf(fmaxf(x, -10.f), 10.f);
    float e = __builtin_amdgcn_exp2f(2.88539008f * x);
    return (e - 1.0f) * __builtin_amdgcn_rcpf(e + 1.0f);
}
__device__ __forceinline__ float b2f(unsigned short u) {
    return __uint_as_float(((unsigned)u) << 16);
}
__device__ __forceinline__ unsigned short f2b(float f) {  // RNE bf16
    unsigned u = __float_as_uint(f);
    return (unsigned short)((u + 0x7FFF + ((u >> 16) & 1)) >> 16);
}

__global__ void f2bf_k(const float* __restrict__ in, unsigned short* __restrict__ out, int n) {
    int i = blockIdx.x * 256 + threadIdx.x;
    if (i < n) out[i] = f2b(in[i]);
}

// Pack W_hh [4D,D] fp32 -> per-(g,dc,wid,kk) contiguous 512-short bf16 chunks
__global__ void packw_k(const float* __restrict__ W, unsigned short* __restrict__ out,
                        int D, int ksh, int dsh) {
    int o = blockIdx.x * 256 + threadIdx.x;
    if (o >= 4 * D * D) return;
    int j  = o & 7;
    int lg = (o >> 3) & 3;
    int lr = (o >> 5) & 15;
    int cch = o >> 9;
    int kk = cch & ((1 << ksh) - 1);
    int c2 = cch >> ksh;
    int wd = c2 & 3;
    int c3 = c2 >> 2;
    int dc = c3 & ((1 << dsh) - 1);
    int g  = c3 >> dsh;
    out[o] = f2b(W[(g * D + dc * 64 + wd * 16 + lr) * D + kk * 32 + lg * 8 + j]);
}

// Pack B [N,K] fp32 -> per-(jt,kk) contiguous 512-short bf16 fragment chunks.
__global__ void packb_k(const float* __restrict__ B, unsigned short* __restrict__ out,
                        int N, int K, int ksh) {
    int o = blockIdx.x * 256 + threadIdx.x;
    if (o >= N * K) return;
    int j  = o & 7;
    int lg = (o >> 3) & 3;
    int lr = (o >> 5) & 15;
    int c  = o >> 9;
    int kk = c & ((1 << ksh) - 1);
    int jt = c >> ksh;
    out[o] = f2b(B[(jt * 16 + lr) * K + kk * 32 + lg * 8 + j]);
}

// ---------------- MFMA bf16 GEMM (r17: 64x128 tile, 2 j-tiles/wave) ----------------
template<bool RELU, bool DUAL, bool BF16OUT, bool PERM>
__global__ __launch_bounds__(256) void gemm_mfma(
    const unsigned short* __restrict__ A,  const unsigned short* __restrict__ Bp,
    const unsigned short* __restrict__ A2, const unsigned short* __restrict__ B2p,
    const float* __restrict__ bias0, const float* __restrict__ bias1,
    void* __restrict__ Cout, int M, int Ncol, int K, int K2, int ksh, int ksh2, int dshD)
{
    __shared__ unsigned short As[64 * 72];   // [64][64+8] bf16
    const int tid  = threadIdx.x;
    const int wid  = tid >> 6;
    const int lane = tid & 63;
    const int lg   = lane >> 4;
    const int lr   = lane & 15;
    const int m0 = blockIdx.y * 64;
    const int j0 = blockIdx.x * 128;
    const int jt0 = (j0 >> 4) + wid * 2;

    f32x4 acc[2][4];   // [j-tile][m-tile]
    #pragma unroll
    for (int jj = 0; jj < 2; ++jj)
        #pragma unroll
        for (int m = 0; m < 4; ++m)
            #pragma unroll
            for (int r = 0; r < 4; ++r) acc[jj][m][r] = 0.f;

    const int npass = DUAL ? 2 : 1;
    for (int pass = 0; pass < npass; ++pass) {
        const unsigned short* Ap  = (DUAL && pass) ? A2  : A;
        const unsigned short* Bpp = (DUAL && pass) ? B2p : Bp;
        const int Kp   = (DUAL && pass) ? K2   : K;
        const int kshp = (DUAL && pass) ? ksh2 : ksh;
        for (int k0 = 0; k0 < Kp; k0 += 64) {
            __syncthreads();   // prev tile consumed
            #pragma unroll
            for (int p = 0; p < 2; ++p) {
                int i = tid + p * 256;
                int row = i >> 3, c16 = i & 7;
                uint4 v = make_uint4(0u, 0u, 0u, 0u);
                if (m0 + row < M) v = *(const uint4*)&Ap[(size_t)(m0 + row) * Kp + k0 + c16 * 8];
                *(uint4*)&As[row * 72 + c16 * 8] = v;
            }
            __syncthreads();
            #pragma unroll
            for (int kk = 0; kk < 2; ++kk) {
                bf16x8 b0 = *(const bf16x8*)&Bpp[(size_t)(((jt0    ) << kshp) + (k0 >> 5) + kk) * 512 + lr * 32 + lg * 8];
                bf16x8 b1 = *(const bf16x8*)&Bpp[(size_t)(((jt0 + 1) << kshp) + (k0 >> 5) + kk) * 512 + lr * 32 + lg * 8];
                #pragma unroll
                for (int m = 0; m < 4; ++m) {
                    bf16x8 a = *(const bf16x8*)&As[(m * 16 + lr) * 72 + kk * 32 + lg * 8];
                    acc[0][m] = __builtin_amdgcn_mfma_f32_16x16x32_bf16(a, b0, acc[0][m], 0, 0, 0);
                    acc[1][m] = __builtin_amdgcn_mfma_f32_16x16x32_bf16(a, b1, acc[1][m], 0, 0, 0);
                }
            }
        }
    }
    #pragma unroll
    for (int jj = 0; jj < 2; ++jj)
        #pragma unroll
        for (int m = 0; m < 4; ++m)
            #pragma unroll
            for (int r = 0; r < 4; ++r) {
                int row = m0 + m * 16 + lg * 4 + r;
                if (row >= M) continue;
                int col = j0 + (wid * 2 + jj) * 16 + lr;
                float v = acc[jj][m][r];
                if (bias0) v += bias0[col];
                if (bias1) v += bias1[col];
                if (RELU) v = fmaxf(v, 0.f);
                if (BF16OUT) {
                    int off = col;
                    if (PERM) {
                        int g   = col >> dshD;
                        int rem = col & ((1 << dshD) - 1);
                        off = (rem >> 6) * 256 + (rem & 63) * 4 + g;
                    }
                    ((unsigned short*)Cout)[(size_t)row * Ncol + off] = f2b(v);
                } else {
                    ((float*)Cout)[(size_t)row * Ncol + col] = v;
                }
            }
}

// ---------------- MFMA fused LSTM (512 thr, TN=64, node-halves share W) -------------
// 8 waves: nh32 = (tid>>8)*32 selects node-half; within a half, wave wid=(tid>>6)&3
// owns d-cols [wid*16,wid*16+16) of each 64-chunk, all 4 gates. Waves w and w+4 read
// the SAME packed-W chunks (node-halves differ, W identical) -> W L2 traffic halves,
// second read L1-hot. Per-thread code = r14: unroll-2 kk, FIFO-correct gather
// ping-pong, gate-interleaved Hin. C-frag: node = nh32 + m*16 + (lane>>4)*4 + reg,
// d = dc*64 + wid*16 + (lane&15).

#define GISSUE(GV, tt, dd)                                                     \
    do {                                                                       \
        _Pragma("unroll")                                                      \
        for (int m_ = 0; m_ < MT; ++m_) {                                      \
            _Pragma("unroll")                                                  \
            for (int r_ = 0; r_ < 4; ++r_) {                                   \
                GV[m_][r_] = *(const uint2*)&Hin[                              \
                    (size_t)nidS[(nh32 + m_ * 16 + lg * 4 + r_) * DEG + (tt)] * FD \
                    + (wid * 16 + lr) * 4 + (dd) * 256];                       \
            }                                                                  \
        }                                                                      \
    } while (0)

#define NONLIN(GV, DC)                                                         \
    do {                                                                       \
        _Pragma("unroll")                                                      \
        for (int m_ = 0; m_ < MT; ++m_) {                                      \
            _Pragma("unroll")                                                  \
            for (int r_ = 0; r_ < 4; ++r_) {                                   \
                uint2 u_ = GV[m_][r_];                                         \
                float g0_ = __uint_as_float(u_.x << 16);                       \
                float g1_ = __uint_as_float(u_.x & 0xFFFF0000u);               \
                float g2_ = __uint_as_float(u_.y << 16);                       \
                float g3_ = __uint_as_float(u_.y & 0xFFFF0000u);               \
                float ig_ = sigf(acc[0][m_][r_] + g0_);                        \
                float fg_ = sigf(acc[1][m_][r_] + g1_);                        \
                float gg_ = tanhf_(acc[2][m_][r_] + g2_);                      \
                float og_ = sigf(acc[3][m_][r_] + g3_);                        \
                float cv_ = fmaf(fg_, c[DC][m_][r_], ig_ * gg_);               \
                c[DC][m_][r_] = cv_;                                           \
                float hv_ = og_ * tanhf_(cv_);                                 \
                if (t < DEG - 1) {                                             \
                    hS[cur ^ 1][(nh32 + m_ * 16 + lg * 4 + r_) * LDA + (DC) * 64 + wid * 16 + lr] = f2b(hv_); \
                } else {                                                       \
                    int node_ = nb + nh32 + m_ * 16 + lg * 4 + r_;             \
                    if (node_ < Nn)                                            \
                        hout[(size_t)node_ * D + (DC) * 64 + wid * 16 + lr] = f2b(hv_); \
                }                                                              \
            }                                                                  \
        }                                                                      \
    } while (0)

template<int D, int MINW>
__global__ __launch_bounds__(512, MINW) void lstm_mfma(
    const unsigned short* __restrict__ Hin,   // [Nn][dc][cc][g] bf16 (bias folded)
    const unsigned short* __restrict__ Wbp,   // packed W_hh (packw_k)
    const int* __restrict__ nidx,             // [Nn,DEG]
    unsigned short* __restrict__ hout,        // [Nn,D] bf16 (standard layout)
    int Nn)
{
    constexpr int FD  = 4 * D;
    constexpr int KCH = D / 32;
    constexpr int DCH = D / 64;
    constexpr int TN  = 64;
    constexpr int MT  = 2;
    constexpr int LDA = D + 8;
    constexpr int GST = DCH * 4 * KCH * 512;

    __shared__ unsigned short hS[2][TN * LDA];   // dbuf h_state
    __shared__ int nidS[TN * DEG];

    const int tid  = threadIdx.x;
    const int wid  = (tid >> 6) & 3;   // d-col wave within half
    const int nh32 = (tid >> 8) * 32;  // node-half base row
    const int lane = tid & 63;
    const int lg   = lane >> 4;
    const int lr   = lane & 15;
    const int nb   = blockIdx.x * TN;

    for (int i = tid; i < TN * DEG; i += 512) {
        int node = nb + (i >> 4);
        nidS[i] = (node < Nn) ? nidx[node * DEG + (i & 15)] : 0;
    }

    float c[DCH][MT][4] = {};         // static indexing only (rule #20)
    uint2 gvA[MT][4], gvB[MT][4];     // ping-pong gather sets (static idx, no & taken)

    __syncthreads();                  // nidS ready
    GISSUE(gvA, 0, 0);                // prologue: fill A for (t=0,dc=0)

    int cur = 0;
    #pragma unroll 1
    for (int t = 0; t < DEG; ++t) {
        #pragma unroll
        for (int dc = 0; dc < DCH; ++dc) {
            f32x4 acc[4][MT];
            #pragma unroll
            for (int g = 0; g < 4; ++g)
                #pragma unroll
                for (int m = 0; m < MT; ++m)
                    #pragma unroll
                    for (int r = 0; r < 4; ++r) acc[g][m][r] = 0.f;

            // recurrent GEMM: acc = h_state @ W_hh^T. Waves w and w+4 read the SAME
            // wb bytes (node-halves share W). unroll-2 caps live W-loads (VGPR diet).
            if (t > 0) {
                const unsigned short* wb = Wbp + ((size_t)dc * 4 + wid) * KCH * 512 + lr * 32 + lg * 8;
                #pragma unroll 2
                for (int kk = 0; kk < KCH; ++kk) {
                    bf16x8 b[4];
                    #pragma unroll
                    for (int g = 0; g < 4; ++g)
                        b[g] = *(const bf16x8*)&wb[g * GST + kk * 512];
                    #pragma unroll
                    for (int m = 0; m < MT; ++m) {
                        bf16x8 a = *(const bf16x8*)&hS[cur][(nh32 + m * 16 + lr) * LDA + kk * 32 + lg * 8];
                        #pragma unroll
                        for (int g = 0; g < 4; ++g)
                            acc[g][m] = __builtin_amdgcn_mfma_f32_16x16x32_bf16(a, b[g], acc[g][m], 0, 0, 0);
                    }
                }
            }

            // issue NEXT iter's gathers here -- after the kk loop's last W wait
            // (vmcnt-FIFO-correct: they ride through nonlin + next iter's W issue).
            __builtin_amdgcn_sched_barrier(0);
            {
                const int dc2 = (dc + 1) % DCH;           // compile-time
                if (dc == DCH - 1) {
                    if (t < DEG - 1) {
                        if ((dc & 1) == 0) GISSUE(gvB, t + 1, dc2);
                        else               GISSUE(gvA, t + 1, dc2);
                    }
                } else {
                    if ((dc & 1) == 0) GISSUE(gvB, t, dc2);
                    else               GISSUE(gvA, t, dc2);
                }
            }

            // nonlinearity consuming this iter's set (filled last iter / prologue)
            if ((dc & 1) == 0) NONLIN(gvA, dc);
            else               NONLIN(gvB, dc);
        }
        __syncthreads();   // once per t: hS[cur^1] visible before next step reads it
        cur ^= 1;
    }
}

// ---------------- readout ----------------
__global__ void segmax_k(const unsigned short* __restrict__ h2, const int* __restrict__ gid,
                         float* __restrict__ hg, int Nn) {
    int g = blockIdx.x;
    int d = threadIdx.x;   // 128
    __shared__ int sb[2];
    if (d < 2) {
        int target = g + d;
        int lo = 0, hi = Nn;
        while (lo < hi) { int mid = (lo + hi) >> 1; if (gid[mid] < target) lo = mid + 1; else hi = mid; }
        sb[d] = lo;
    }
    __syncthreads();
    int lo = sb[0], hi = sb[1];
    float m = -INFINITY;
    for (int r = lo; r < hi; ++r) m = fmaxf(m, b2f(h2[(size_t)r * HIDDIM + d]));
    hg[g * HIDDIM + d] = m;
}

__global__ void cls_k(const float* __restrict__ hg, const float* __restrict__ W,
                      const float* __restrict__ b, float* __restrict__ out) {
    int idx = blockIdx.x * 256 + threadIdx.x;
    if (idx >= NGRAPH * NCLS) return;
    int g = idx / NCLS, cc = idx % NCLS;
    float s = b[cc];
    const float* hp = hg + g * HIDDIM;
    const float* wp = W + cc * HIDDIM;
    #pragma unroll 8
    for (int k = 0; k < HIDDIM; ++k) s = fmaf(hp[k], wp[k], s);
    out[idx] = s;
}

extern "C" void kernel_launch(void* const* d_in, const int* in_sizes, int n_in,
                              void* d_out, int out_size, void* d_ws, size_t ws_size,
                              hipStream_t stream)
{
    const float* h       = (const float*)d_in[0];
    const int*   nidx    = (const int*)d_in[1];
    const int*   gids    = (const int*)d_in[2];
    const float* W_ih1   = (const float*)d_in[3];
    const float* W_hh1   = (const float*)d_in[4];
    const float* b_ih1   = (const float*)d_in[5];
    const float* b_hh1   = (const float*)d_in[6];
    const float* W_self1 = (const float*)d_in[7];
    const float* W_neigh1= (const float*)d_in[8];
    const float* b1      = (const float*)d_in[9];
    const float* W_ih2   = (const float*)d_in[10];
    const float* W_hh2   = (const float*)d_in[11];
    const float* b_ih2   = (const float*)d_in[12];
    const float* b_hh2   = (const float*)d_in[13];
    const float* W_self2 = (const float*)d_in[14];
    const float* W_neigh2= (const float*)d_in[15];
    const float* b2      = (const float*)d_in[16];
    const float* W_cls   = (const float*)d_in[17];
    const float* b_cls   = (const float*)d_in[18];
    float* out = (float*)d_out;

    // ws layout (bf16 activations)
    char* ws = (char*)d_ws;
    unsigned short* Hin   = (unsigned short*)(ws);             // 102,400,000
    unsigned short* hb    = (unsigned short*)(ws + 102400000); //  25,600,000
    unsigned short* hnb   = (unsigned short*)(ws + 128000000); //  25,600,000 (lstm out)
    unsigned short* h1b   = (unsigned short*)(ws + 153600000); //  12,800,000
    unsigned short* h2b   = (unsigned short*)(ws + 166400000); //  12,800,000
    float*          hg    = (float*)(ws + 179200000);          //     131,072
    unsigned short* Whh1p = (unsigned short*)(ws + 179331072); //     524,288
    unsigned short* Whh2p = (unsigned short*)(ws + 179855360); //     131,072
    unsigned short* Wih1p = (unsigned short*)(ws + 179986432); //     524,288
    unsigned short* Wih2p = (unsigned short*)(ws + 180510720); //     131,072
    unsigned short* Wsl1p = (unsigned short*)(ws + 180641792); //      65,536
    unsigned short* Wng1p = (unsigned short*)(ws + 180707328); //      65,536
    unsigned short* Wsl2p = (unsigned short*)(ws + 180772864); //      32,768
    unsigned short* Wng2p = (unsigned short*)(ws + 180805632); //      32,768

    // prep: conversions + packing (all tiny)
    f2bf_k<<<dim3(50000), 256, 0, stream>>>(h, hb, NNODES * INDIM);
    packw_k<<<dim3(1024), 256, 0, stream>>>(W_hh1, Whh1p, 256, 3, 2);
    packw_k<<<dim3(256), 256, 0, stream>>>(W_hh2, Whh2p, 128, 2, 1);
    packb_k<<<dim3(1024), 256, 0, stream>>>(W_ih1, Wih1p, 1024, 256, 3);
    packb_k<<<dim3(256), 256, 0, stream>>>(W_ih2, Wih2p, 512, 128, 2);
    packb_k<<<dim3(128), 256, 0, stream>>>(W_self1, Wsl1p, 128, 256, 3);
    packb_k<<<dim3(128), 256, 0, stream>>>(W_neigh1, Wng1p, 128, 256, 3);
    packb_k<<<dim3(64), 256, 0, stream>>>(W_self2, Wsl2p, 128, 128, 2);
    packb_k<<<dim3(64), 256, 0, stream>>>(W_neigh2, Wng2p, 128, 128, 2);

    const int MB = (NNODES + 63) / 64;     // 782
    const int NB64 = (NNODES + 63) / 64;   // 782 LSTM blocks (64 nodes each)

    // ---- conv1 ----
    gemm_mfma<false, false, true, true><<<dim3(1024 / 128, MB), 256, 0, stream>>>(
        hb, Wih1p, nullptr, nullptr, b_ih1, b_hh1, Hin, NNODES, 1024, 256, 0, 3, 0, 8);
    lstm_mfma<256, 1><<<dim3(NB64), 512, 0, stream>>>(Hin, Whh1p, nidx, hnb, NNODES);
    gemm_mfma<true, true, true, false><<<dim3(HIDDIM / 128, MB), 256, 0, stream>>>(
        hb, Wsl1p, hnb, Wng1p, b1, nullptr, h1b, NNODES, HIDDIM, 256, 256, 3, 3, 0);

    // ---- conv2 ----
    gemm_mfma<false, false, true, true><<<dim3(512 / 128, MB), 256, 0, stream>>>(
        h1b, Wih2p, nullptr, nullptr, b_ih2, b_hh2, Hin, NNODES, 512, 128, 0, 2, 0, 7);
    lstm_mfma<128, 1><<<dim3(NB64), 512, 0, stream>>>(Hin, Whh2p, nidx, hnb, NNODES);
    gemm_mfma<true, true, true, false><<<dim3(HIDDIM / 128, MB), 256, 0, stream>>>(
        h1b, Wsl2p, hnb, Wng2p, b2, nullptr, h2b, NNODES, HIDDIM, 128, 128, 2, 2, 0);

    // ---- readout ----
    segmax_k<<<dim3(NGRAPH), 128, 0, stream>>>(h2b, gids, hg, NNODES);
    cls_k<<<dim3((NGRAPH * NCLS + 255) / 256), 256, 0, stream>>>(hg, W_cls, b_cls, out);
}

// Round 19
// 1583.792 us; speedup vs baseline: 1.1900x; 1.1900x over previous
//
#include <hip/hip_runtime.h>
#include <hip/hip_bf16.h>

// SAGEClassifier: h[50000,256] --conv1(LSTM-agg)--> h1[50000,128] --conv2--> h2[50000,128]
//   --segment_max(256 graphs)--> hg[256,128] --linear--> out[256,10]
//
// Round 19: REVERT r18 (W-sharing ran clean, still -16%: W-BW was never the limiter;
// 8-wave barriers cost more). REVERT r17's GEMM widening (neutral). Base = r14 exact
// (session best, 1591us). ONE probe: s_setprio(1) around the kk MFMA loop (T5) --
// blocks here are independent and phase-diverse (the m191-attn regime where setprio
// paid +4-7%, not the m190 lockstep-GEMM regime where it was null).

#define NNODES  50000
#define DEG     16
#define INDIM   256
#define HIDDIM  128
#define NCLS    10
#define NGRAPH  256

typedef __hip_bfloat16 bf16;
typedef short bf16x8 __attribute__((ext_vector_type(8)));
typedef float f32x4  __attribute__((ext_vector_type(4)));

__device__ __forceinline__ float sigf(float x) {
    float e = __builtin_amdgcn_exp2f(-1.44269504f * x);
    return __builtin_amdgcn_rcpf(1.0f + e);
}
__device__ __forceinline__ float tanhf_(float x) {
    x = fminf(fmaxf(x, -10.f), 10.f);
    float e = __builtin_amdgcn_exp2f(2.88539008f * x);
    return (e - 1.0f) * __builtin_amdgcn_rcpf(e + 1.0f);
}
__device__ __forceinline__ float b2f(unsigned short u) {
    return __uint_as_float(((unsigned)u) << 16);
}
__device__ __forceinline__ unsigned short f2b(float f) {  // RNE bf16
    unsigned u = __float_as_uint(f);
    return (unsigned short)((u + 0x7FFF + ((u >> 16) & 1)) >> 16);
}

__global__ void f2bf_k(const float* __restrict__ in, unsigned short* __restrict__ out, int n) {
    int i = blockIdx.x * 256 + threadIdx.x;
    if (i < n) out[i] = f2b(in[i]);
}

// Pack W_hh [4D,D] fp32 -> per-(g,dc,wid,kk) contiguous 512-short bf16 chunks
__global__ void packw_k(const float* __restrict__ W, unsigned short* __restrict__ out,
                        int D, int ksh, int dsh) {
    int o = blockIdx.x * 256 + threadIdx.x;
    if (o >= 4 * D * D) return;
    int j  = o & 7;
    int lg = (o >> 3) & 3;
    int lr = (o >> 5) & 15;
    int cch = o >> 9;
    int kk = cch & ((1 << ksh) - 1);
    int c2 = cch >> ksh;
    int wd = c2 & 3;
    int c3 = c2 >> 2;
    int dc = c3 & ((1 << dsh) - 1);
    int g  = c3 >> dsh;
    out[o] = f2b(W[(g * D + dc * 64 + wd * 16 + lr) * D + kk * 32 + lg * 8 + j]);
}

// Pack B [N,K] fp32 -> per-(jt,kk) contiguous 512-short bf16 fragment chunks.
__global__ void packb_k(const float* __restrict__ B, unsigned short* __restrict__ out,
                        int N, int K, int ksh) {
    int o = blockIdx.x * 256 + threadIdx.x;
    if (o >= N * K) return;
    int j  = o & 7;
    int lg = (o >> 3) & 3;
    int lr = (o >> 5) & 15;
    int c  = o >> 9;
    int kk = c & ((1 << ksh) - 1);
    int jt = c >> ksh;
    out[o] = f2b(B[(jt * 16 + lr) * K + kk * 32 + lg * 8 + j]);
}

// ---------------- MFMA bf16 GEMM (r14: 64x64 tile, 1 j-tile/wave) ----------------
// PERM: write bf16 output gate-interleaved: logical col = g*D + dc*64 + cc  ->
// offset dc*256 + cc*4 + g  (requires BF16OUT; dshD = log2(D)).
template<bool RELU, bool DUAL, bool BF16OUT, bool PERM>
__global__ __launch_bounds__(256) void gemm_mfma(
    const unsigned short* __restrict__ A,  const unsigned short* __restrict__ Bp,
    const unsigned short* __restrict__ A2, const unsigned short* __restrict__ B2p,
    const float* __restrict__ bias0, const float* __restrict__ bias1,
    void* __restrict__ Cout, int M, int Ncol, int K, int K2, int ksh, int ksh2, int dshD)
{
    __shared__ unsigned short As[64 * 72];   // [64][64+8] bf16
    const int tid  = threadIdx.x;
    const int wid  = tid >> 6;
    const int lane = tid & 63;
    const int lg   = lane >> 4;
    const int lr   = lane & 15;
    const int m0 = blockIdx.y * 64;
    const int j0 = blockIdx.x * 64;
    const int jt = (j0 >> 4) + wid;

    f32x4 acc[4];
    #pragma unroll
    for (int m = 0; m < 4; ++m)
        #pragma unroll
        for (int r = 0; r < 4; ++r) acc[m][r] = 0.f;

    const int npass = DUAL ? 2 : 1;
    for (int pass = 0; pass < npass; ++pass) {
        const unsigned short* Ap  = (DUAL && pass) ? A2  : A;
        const unsigned short* Bpp = (DUAL && pass) ? B2p : Bp;
        const int Kp   = (DUAL && pass) ? K2   : K;
        const int kshp = (DUAL && pass) ? ksh2 : ksh;
        for (int k0 = 0; k0 < Kp; k0 += 64) {
            __syncthreads();   // prev tile consumed
            #pragma unroll
            for (int p = 0; p < 2; ++p) {
                int i = tid + p * 256;
                int row = i >> 3, c16 = i & 7;
                uint4 v = make_uint4(0u, 0u, 0u, 0u);
                if (m0 + row < M) v = *(const uint4*)&Ap[(size_t)(m0 + row) * Kp + k0 + c16 * 8];
                *(uint4*)&As[row * 72 + c16 * 8] = v;
            }
            __syncthreads();
            #pragma unroll
            for (int kk = 0; kk < 2; ++kk) {
                bf16x8 b = *(const bf16x8*)&Bpp[(size_t)((jt << kshp) + (k0 >> 5) + kk) * 512 + lr * 32 + lg * 8];
                #pragma unroll
                for (int m = 0; m < 4; ++m) {
                    bf16x8 a = *(const bf16x8*)&As[(m * 16 + lr) * 72 + kk * 32 + lg * 8];
                    acc[m] = __builtin_amdgcn_mfma_f32_16x16x32_bf16(a, b, acc[m], 0, 0, 0);
                }
            }
        }
    }
    #pragma unroll
    for (int m = 0; m < 4; ++m)
        #pragma unroll
        for (int r = 0; r < 4; ++r) {
            int row = m0 + m * 16 + lg * 4 + r;
            if (row >= M) continue;
            int col = j0 + wid * 16 + lr;
            float v = acc[m][r];
            if (bias0) v += bias0[col];
            if (bias1) v += bias1[col];
            if (RELU) v = fmaxf(v, 0.f);
            if (BF16OUT) {
                int off = col;
                if (PERM) {
                    int g   = col >> dshD;
                    int rem = col & ((1 << dshD) - 1);
                    off = (rem >> 6) * 256 + (rem & 63) * 4 + g;
                }
                ((unsigned short*)Cout)[(size_t)row * Ncol + off] = f2b(v);
            } else {
                ((float*)Cout)[(size_t)row * Ncol + col] = v;
            }
        }
}

// ---------------- MFMA fused LSTM (r14 + setprio around kk MFMA loop) ----------------
// 32 nodes/block, 4 waves. Wave w owns d-cols [w*16,w*16+16) of each 64-chunk, all 4
// gates -> i/f/g/o of a (node,d) share a lane+reg. C-frag: node=m*16+(lane>>4)*4+reg,
// d = dc*64 + w*16 + (lane&15). Hin gate-interleaved [node][dc][cc][g]: one 8B load
// per (node,d) = all 4 gates. Gathers for iter ii+1 issue AFTER iter ii's kk loop.
// kk loop unroll-2 (register diet). setprio(1) favors MFMA-phase waves over
// co-resident blocks in gather/nonlin phases (independent-block regime, T5/m191).

#define GISSUE(GV, tt, dd)                                                     \
    do {                                                                       \
        _Pragma("unroll")                                                      \
        for (int m_ = 0; m_ < MT; ++m_) {                                      \
            _Pragma("unroll")                                                  \
            for (int r_ = 0; r_ < 4; ++r_) {                                   \
                GV[m_][r_] = *(const uint2*)&Hin[                              \
                    (size_t)nidS[(m_ * 16 + lg * 4 + r_) * DEG + (tt)] * FD    \
                    + (wid * 16 + lr) * 4 + (dd) * 256];                       \
            }                                                                  \
        }                                                                      \
    } while (0)

#define NONLIN(GV, DC)                                                         \
    do {                                                                       \
        _Pragma("unroll")                                                      \
        for (int m_ = 0; m_ < MT; ++m_) {                                      \
            _Pragma("unroll")                                                  \
            for (int r_ = 0; r_ < 4; ++r_) {                                   \
                uint2 u_ = GV[m_][r_];                                         \
                float g0_ = __uint_as_float(u_.x << 16);                       \
                float g1_ = __uint_as_float(u_.x & 0xFFFF0000u);               \
                float g2_ = __uint_as_float(u_.y << 16);                       \
                float g3_ = __uint_as_float(u_.y & 0xFFFF0000u);               \
                float ig_ = sigf(acc[0][m_][r_] + g0_);                        \
                float fg_ = sigf(acc[1][m_][r_] + g1_);                        \
                float gg_ = tanhf_(acc[2][m_][r_] + g2_);                      \
                float og_ = sigf(acc[3][m_][r_] + g3_);                        \
                float cv_ = fmaf(fg_, c[DC][m_][r_], ig_ * gg_);               \
                c[DC][m_][r_] = cv_;                                           \
                float hv_ = og_ * tanhf_(cv_);                                 \
                if (t < DEG - 1) {                                             \
                    hS[cur ^ 1][(m_ * 16 + lg * 4 + r_) * LDA + (DC) * 64 + wid * 16 + lr] = f2b(hv_); \
                } else {                                                       \
                    int node_ = nb + m_ * 16 + lg * 4 + r_;                    \
                    if (node_ < Nn)                                            \
                        hout[(size_t)node_ * D + (DC) * 64 + wid * 16 + lr] = f2b(hv_); \
                }                                                              \
            }                                                                  \
        }                                                                      \
    } while (0)

template<int D, int MINW>
__global__ __launch_bounds__(256, MINW) void lstm_mfma(
    const unsigned short* __restrict__ Hin,   // [Nn][dc][cc][g] bf16 (bias folded)
    const unsigned short* __restrict__ Wbp,   // packed W_hh (packw_k)
    const int* __restrict__ nidx,             // [Nn,DEG]
    unsigned short* __restrict__ hout,        // [Nn,D] bf16 (standard layout)
    int Nn)
{
    constexpr int FD  = 4 * D;
    constexpr int KCH = D / 32;
    constexpr int DCH = D / 64;
    constexpr int TN  = 32;
    constexpr int MT  = 2;
    constexpr int LDA = D + 8;
    constexpr int GST = DCH * 4 * KCH * 512;

    __shared__ unsigned short hS[2][TN * LDA];   // dbuf h_state (only shared state)
    __shared__ int nidS[TN * DEG];

    const int tid  = threadIdx.x;
    const int wid  = tid >> 6;
    const int lane = tid & 63;
    const int lg   = lane >> 4;
    const int lr   = lane & 15;
    const int nb   = blockIdx.x * TN;

    for (int i = tid; i < TN * DEG; i += 256) {
        int node = nb + (i >> 4);
        nidS[i] = (node < Nn) ? nidx[node * DEG + (i & 15)] : 0;
    }

    float c[DCH][MT][4] = {};         // static indexing only (rule #20)
    uint2 gvA[MT][4], gvB[MT][4];     // ping-pong gather sets (static idx, no & taken)

    __syncthreads();                  // nidS ready
    GISSUE(gvA, 0, 0);                // prologue: fill A for (t=0,dc=0)

    int cur = 0;
    #pragma unroll 1
    for (int t = 0; t < DEG; ++t) {
        #pragma unroll
        for (int dc = 0; dc < DCH; ++dc) {
            f32x4 acc[4][MT];
            #pragma unroll
            for (int g = 0; g < 4; ++g)
                #pragma unroll
                for (int m = 0; m < MT; ++m)
                    #pragma unroll
                    for (int r = 0; r < 4; ++r) acc[g][m][r] = 0.f;

            // recurrent GEMM: acc = h_state @ W_hh^T (wave's col slice).
            // unroll-2: limits live W-loads to ~8 (register diet -> occupancy).
            // setprio(1): favor this wave while it feeds the matrix pipe.
            if (t > 0) {
                const unsigned short* wb = Wbp + ((size_t)dc * 4 + wid) * KCH * 512 + lr * 32 + lg * 8;
                __builtin_amdgcn_s_setprio(1);
                #pragma unroll 2
                for (int kk = 0; kk < KCH; ++kk) {
                    bf16x8 b[4];
                    #pragma unroll
                    for (int g = 0; g < 4; ++g)
                        b[g] = *(const bf16x8*)&wb[g * GST + kk * 512];
                    #pragma unroll
                    for (int m = 0; m < MT; ++m) {
                        bf16x8 a = *(const bf16x8*)&hS[cur][(m * 16 + lr) * LDA + kk * 32 + lg * 8];
                        #pragma unroll
                        for (int g = 0; g < 4; ++g)
                            acc[g][m] = __builtin_amdgcn_mfma_f32_16x16x32_bf16(a, b[g], acc[g][m], 0, 0, 0);
                    }
                }
                __builtin_amdgcn_s_setprio(0);
            }

            // issue NEXT iter's gathers here -- after the kk loop's last W wait, so
            // they ride in flight through nonlin + next iter's W issue (FIFO-correct).
            __builtin_amdgcn_sched_barrier(0);
            {
                const int dc2 = (dc + 1) % DCH;           // compile-time
                if (dc == DCH - 1) {
                    if (t < DEG - 1) {
                        if ((dc & 1) == 0) GISSUE(gvB, t + 1, dc2);
                        else               GISSUE(gvA, t + 1, dc2);
                    }
                } else {
                    if ((dc & 1) == 0) GISSUE(gvB, t, dc2);
                    else               GISSUE(gvA, t, dc2);
                }
            }

            // nonlinearity consuming this iter's set (filled last iter / prologue)
            if ((dc & 1) == 0) NONLIN(gvA, dc);
            else               NONLIN(gvB, dc);
        }
        __syncthreads();   // once per t: hS[cur^1] visible before next step reads it
        cur ^= 1;
    }
}

// ---------------- readout ----------------
__global__ void segmax_k(const unsigned short* __restrict__ h2, const int* __restrict__ gid,
                         float* __restrict__ hg, int Nn) {
    int g = blockIdx.x;
    int d = threadIdx.x;   // 128
    __shared__ int sb[2];
    if (d < 2) {
        int target = g + d;
        int lo = 0, hi = Nn;
        while (lo < hi) { int mid = (lo + hi) >> 1; if (gid[mid] < target) lo = mid + 1; else hi = mid; }
        sb[d] = lo;
    }
    __syncthreads();
    int lo = sb[0], hi = sb[1];
    float m = -INFINITY;
    for (int r = lo; r < hi; ++r) m = fmaxf(m, b2f(h2[(size_t)r * HIDDIM + d]));
    hg[g * HIDDIM + d] = m;
}

__global__ void cls_k(const float* __restrict__ hg, const float* __restrict__ W,
                      const float* __restrict__ b, float* __restrict__ out) {
    int idx = blockIdx.x * 256 + threadIdx.x;
    if (idx >= NGRAPH * NCLS) return;
    int g = idx / NCLS, cc = idx % NCLS;
    float s = b[cc];
    const float* hp = hg + g * HIDDIM;
    const float* wp = W + cc * HIDDIM;
    #pragma unroll 8
    for (int k = 0; k < HIDDIM; ++k) s = fmaf(hp[k], wp[k], s);
    out[idx] = s;
}

extern "C" void kernel_launch(void* const* d_in, const int* in_sizes, int n_in,
                              void* d_out, int out_size, void* d_ws, size_t ws_size,
                              hipStream_t stream)
{
    const float* h       = (const float*)d_in[0];
    const int*   nidx    = (const int*)d_in[1];
    const int*   gids    = (const int*)d_in[2];
    const float* W_ih1   = (const float*)d_in[3];
    const float* W_hh1   = (const float*)d_in[4];
    const float* b_ih1   = (const float*)d_in[5];
    const float* b_hh1   = (const float*)d_in[6];
    const float* W_self1 = (const float*)d_in[7];
    const float* W_neigh1= (const float*)d_in[8];
    const float* b1      = (const float*)d_in[9];
    const float* W_ih2   = (const float*)d_in[10];
    const float* W_hh2   = (const float*)d_in[11];
    const float* b_ih2   = (const float*)d_in[12];
    const float* b_hh2   = (const float*)d_in[13];
    const float* W_self2 = (const float*)d_in[14];
    const float* W_neigh2= (const float*)d_in[15];
    const float* b2      = (const float*)d_in[16];
    const float* W_cls   = (const float*)d_in[17];
    const float* b_cls   = (const float*)d_in[18];
    float* out = (float*)d_out;

    // ws layout (bf16 activations)
    char* ws = (char*)d_ws;
    unsigned short* Hin   = (unsigned short*)(ws);             // 102,400,000
    unsigned short* hb    = (unsigned short*)(ws + 102400000); //  25,600,000
    unsigned short* hnb   = (unsigned short*)(ws + 128000000); //  25,600,000 (lstm out)
    unsigned short* h1b   = (unsigned short*)(ws + 153600000); //  12,800,000
    unsigned short* h2b   = (unsigned short*)(ws + 166400000); //  12,800,000
    float*          hg    = (float*)(ws + 179200000);          //     131,072
    unsigned short* Whh1p = (unsigned short*)(ws + 179331072); //     524,288
    unsigned short* Whh2p = (unsigned short*)(ws + 179855360); //     131,072
    unsigned short* Wih1p = (unsigned short*)(ws + 179986432); //     524,288
    unsigned short* Wih2p = (unsigned short*)(ws + 180510720); //     131,072
    unsigned short* Wsl1p = (unsigned short*)(ws + 180641792); //      65,536
    unsigned short* Wng1p = (unsigned short*)(ws + 180707328); //      65,536
    unsigned short* Wsl2p = (unsigned short*)(ws + 180772864); //      32,768
    unsigned short* Wng2p = (unsigned short*)(ws + 180805632); //      32,768

    // prep: conversions + packing (all tiny)
    f2bf_k<<<dim3(50000), 256, 0, stream>>>(h, hb, NNODES * INDIM);
    packw_k<<<dim3(1024), 256, 0, stream>>>(W_hh1, Whh1p, 256, 3, 2);
    packw_k<<<dim3(256), 256, 0, stream>>>(W_hh2, Whh2p, 128, 2, 1);
    packb_k<<<dim3(1024), 256, 0, stream>>>(W_ih1, Wih1p, 1024, 256, 3);
    packb_k<<<dim3(256), 256, 0, stream>>>(W_ih2, Wih2p, 512, 128, 2);
    packb_k<<<dim3(128), 256, 0, stream>>>(W_self1, Wsl1p, 128, 256, 3);
    packb_k<<<dim3(128), 256, 0, stream>>>(W_neigh1, Wng1p, 128, 256, 3);
    packb_k<<<dim3(64), 256, 0, stream>>>(W_self2, Wsl2p, 128, 128, 2);
    packb_k<<<dim3(64), 256, 0, stream>>>(W_neigh2, Wng2p, 128, 128, 2);

    const int MB = (NNODES + 63) / 64;     // 782
    const int NB32 = (NNODES + 31) / 32;   // 1563

    // ---- conv1 ----
    gemm_mfma<false, false, true, true><<<dim3(1024 / 64, MB), 256, 0, stream>>>(
        hb, Wih1p, nullptr, nullptr, b_ih1, b_hh1, Hin, NNODES, 1024, 256, 0, 3, 0, 8);
    lstm_mfma<256, 1><<<dim3(NB32), 256, 0, stream>>>(Hin, Whh1p, nidx, hnb, NNODES);
    gemm_mfma<true, true, true, false><<<dim3(HIDDIM / 64, MB), 256, 0, stream>>>(
        hb, Wsl1p, hnb, Wng1p, b1, nullptr, h1b, NNODES, HIDDIM, 256, 256, 3, 3, 0);

    // ---- conv2 ----
    gemm_mfma<false, false, true, true><<<dim3(512 / 64, MB), 256, 0, stream>>>(
        h1b, Wih2p, nullptr, nullptr, b_ih2, b_hh2, Hin, NNODES, 512, 128, 0, 2, 0, 7);
    lstm_mfma<128, 1><<<dim3(NB32), 256, 0, stream>>>(Hin, Whh2p, nidx, hnb, NNODES);
    gemm_mfma<true, true, true, false><<<dim3(HIDDIM / 64, MB), 256, 0, stream>>>(
        h1b, Wsl2p, hnb, Wng2p, b2, nullptr, h2b, NNODES, HIDDIM, 128, 128, 2, 2, 0);

    // ---- readout ----
    segmax_k<<<dim3(NGRAPH), 128, 0, stream>>>(h2b, gids, hg, NNODES);
    cls_k<<<dim3((NGRAPH * NCLS + 255) / 256), 256, 0, stream>>>(hg, W_cls, b_cls, out);
}